// Round 6
// baseline (396.425 us; speedup 1.0000x reference)
//
#include <hip/hip_runtime.h>
#include <stdint.h>

// out[b][o] = clamp((sum_k x[b][k]*W[o][k] + t[o]) >> (-n[o]), act_min[o], act_max[o])
// B=8192, IN=4096, OUT=4096. x,W arrive int32; harness reads d_out as int32.
//
// R16: deep pipeline + read/MFMA overlap. Cycle accounting of R12-R15 (all
// 46-50%): per set, MFMA window 585 cy/SIMD and LDS-read window 576 cy/CU were
// SERIALIZED -- R15 by disjoint barrier windows, R12/R13 by vmcnt(2) waiting on
// loads only ~600cy old (< 900cy HBM latency). Fix: 6 LDS buffers (96 KB),
// stage distance +5, vmcnt(6) waits on loads staged 4 phases (~2400cy) ago.
// One barrier/phase: vmcnt(6) -> barrier -> stage k+5 -> ds_read set k+1 (no
// consumer this phase) -> MFMA set k (operands from last phase; counted lgkm
// passes free). LDS port and MFMA pipe now co-resident in every phase.

#define BDIM 8192
#define INDIM 4096
#define OUTDIM 4096

typedef __attribute__((ext_vector_type(4))) int I4;
typedef __attribute__((ext_vector_type(16))) int I16;

// ---------------- pack: int32 -> int8 fragment order, LDS transpose ----------
// Fragment layout: byte off = ((m32*128 + kb)*64 + lane)*16 + b,
// where row = m32*32 + (lane&31), k = kb*32 + (lane>>5)*16 + b.
__global__ __launch_bounds__(256) void pack_lds(const int* __restrict__ x,
                                                const int* __restrict__ W,
                                                uint32_t* __restrict__ xp,
                                                uint32_t* __restrict__ wp) {
    __shared__ uint32_t sb[8192];  // 32 KB
    const int tid = threadIdx.x;
    const int bid = blockIdx.x;
    const int* src;
    uint32_t* dst;
    if (bid < 1024) {
        const int m32 = bid >> 2, q = bid & 3;
        src = x + (size_t)m32 * 32 * INDIM + q * 1024;
        dst = xp + (size_t)m32 * 32768 + q * 8192;
    } else {
        const int v = bid - 1024;
        const int n32 = v >> 2, q = v & 3;
        src = W + (size_t)n32 * 32 * INDIM + q * 1024;
        dst = wp + (size_t)n32 * 32768 + q * 8192;
    }
    const int kb_l = tid >> 3;                 // local kb (k/32 within chunk)
    const int lane_hi = ((tid >> 2) & 1) << 5; // (k>>4)&1 -> lane bit 5
    const int bslot = tid & 3;                 // byte-word slot within lane's 16B
#pragma unroll 4
    for (int rr = 0; rr < 32; ++rr) {
        int4 a = *(const int4*)(src + (size_t)rr * INDIM + tid * 4);
        uint32_t v = ((uint32_t)a.x & 255u) | (((uint32_t)a.y & 255u) << 8)
                   | (((uint32_t)a.z & 255u) << 16) | (((uint32_t)a.w & 255u) << 24);
        uint32_t idx = (uint32_t)(kb_l * 256 + (rr + lane_hi) * 4 + bslot);
        idx ^= ((idx >> 8) & 7u) << 2;  // XOR-swizzle: 16-way -> 2-way (free)
        sb[idx] = v;
    }
    __syncthreads();
#pragma unroll
    for (int it = 0; it < 8; ++it) {
        uint32_t idx = (uint32_t)(it * 1024 + tid * 4);
        idx ^= ((idx >> 8) & 7u) << 2;
        uint4 vv = *(const uint4*)&sb[idx];
        *(uint4*)(dst + it * 1024 + tid * 4) = vv;
    }
}

// ---------------- GEMM: 8 waves/block, 256x256 tile, wave tile 128x64 --------
__device__ __forceinline__ void glds16(const void* g, void* l) {
    __builtin_amdgcn_global_load_lds((__attribute__((address_space(1))) void*)g,
                                     (__attribute__((address_space(3))) void*)l,
                                     16, 0, 0);
}

#define VMW8() asm volatile("s_waitcnt vmcnt(8)" ::: "memory")
#define VMW6() asm volatile("s_waitcnt vmcnt(6)" ::: "memory")
#define VMW4() asm volatile("s_waitcnt vmcnt(4)" ::: "memory")
#define VMW2() asm volatile("s_waitcnt vmcnt(2)" ::: "memory")
#define VMW0() asm volatile("s_waitcnt vmcnt(0)" ::: "memory")
#define LGKM0() asm volatile("s_waitcnt lgkmcnt(0)" ::: "memory")
#define BARRIER()                          \
    do {                                   \
        __builtin_amdgcn_s_barrier();      \
        asm volatile("" ::: "memory");     \
    } while (0)
#define SCHEDB() __builtin_amdgcn_sched_barrier(0)

// stage set SETK into buffer BUF (0..5): this wave's 2 subtiles (1 KB each)
#define STAGE(SETK, BUF)                                                          \
    do {                                                                          \
        _Pragma("unroll")                                                         \
        for (int i_ = 0; i_ < 2; ++i_)                                            \
            glds16(gsrc[i_] + (size_t)(SETK) * 1024,                              \
                   lds_raw + (BUF) * 16384 + (w * 2 + i_) * 1024);                \
    } while (0)

// read this wave's 6 fragments of one set from buffer BUF (compile-time 0..5)
#define FRAG_READ(FA, FB, BUF)                                                    \
    do {                                                                          \
        const uint8_t* lb_ = lds_raw + (BUF) * 16384 + lane * 16;                 \
        _Pragma("unroll")                                                         \
        for (int i_ = 0; i_ < 4; ++i_)                                            \
            FA[i_] = *(const I4*)(lb_ + (wr4 + i_) * 1024);                       \
        _Pragma("unroll")                                                         \
        for (int j_ = 0; j_ < 2; ++j_)                                            \
            FB[j_] = *(const I4*)(lb_ + 8192 + (wc2 + j_) * 1024);                \
    } while (0)

#define MFMA_SET(FA, FB)                                                          \
    do {                                                                          \
        __builtin_amdgcn_s_setprio(1);                                            \
        _Pragma("unroll")                                                         \
        for (int i_ = 0; i_ < 4; ++i_)                                            \
            _Pragma("unroll")                                                     \
            for (int j_ = 0; j_ < 2; ++j_)                                        \
                acc[i_][j_] = __builtin_amdgcn_mfma_i32_32x32x32_i8(              \
                    FA[i_], FB[j_], acc[i_][j_], 0, 0, 0);                        \
        __builtin_amdgcn_s_setprio(0);                                            \
    } while (0)

// Phase for set k: confirm(vmcnt) -> publish(barrier) -> stage set k+5 ->
// read set k+1 (regs R*) -> MFMA set k (regs M*). Reads overlap MFMAs.
#define PH_S(VMW_STMT, SSET, SBUF, RBUF, RA, RB, MA, MB)                          \
    do {                                                                          \
        VMW_STMT;                                                                 \
        BARRIER();                                                                \
        STAGE(SSET, SBUF);                                                        \
        FRAG_READ(RA, RB, RBUF);                                                  \
        MFMA_SET(MA, MB);                                                         \
        SCHEDB();                                                                 \
    } while (0)

#define PH_N(VMW_STMT, RBUF, RA, RB, MA, MB)                                      \
    do {                                                                          \
        VMW_STMT;                                                                 \
        BARRIER();                                                                \
        FRAG_READ(RA, RB, RBUF);                                                  \
        MFMA_SET(MA, MB);                                                         \
        SCHEDB();                                                                 \
    } while (0)

__global__ __launch_bounds__(512, 2) void gemm_lds(
    const uint8_t* __restrict__ Xp,   // fragment-ordered
    const uint8_t* __restrict__ Wp,   // fragment-ordered
    const int* __restrict__ t, const int* __restrict__ nsh,
    const int* __restrict__ amin, const int* __restrict__ amax,
    int* __restrict__ out) {

    const int bn = blockIdx.x;       // 0..15 (OUT tiles of 256) — fast axis
    const int bm = blockIdx.y;       // 0..31
    const int tid = threadIdx.x;
    const int lane = tid & 63;
    const int w = tid >> 6;          // wave 0..7
    const int wr = w >> 2;           // wave row (0..1): rows wr*128..+128
    const int wc = w & 3;            // wave col (0..3): cols wc*64..+64
    const int wr4 = wr * 4;
    const int wc2 = wc * 2;

    __shared__ uint8_t lds_raw[98304];  // 6 buffers x (8 A + 8 B subtiles) x 1 KB

    // wave w stages subtiles s = 2w, 2w+1 (s<8: A row-tiles; s>=8: B col-tiles)
    const uint8_t* gsrc[2];
#pragma unroll
    for (int i = 0; i < 2; ++i) {
        const int s = w * 2 + i;
        gsrc[i] = (s < 8) ? Xp + ((size_t)(bm * 8 + s) << 17) + lane * 16
                          : Wp + ((size_t)(bn * 8 + (s - 8)) << 17) + lane * 16;
    }

    I16 acc[4][2];
#pragma unroll
    for (int i = 0; i < 4; ++i)
#pragma unroll
        for (int j = 0; j < 2; ++j)
#pragma unroll
            for (int r = 0; r < 16; ++r) acc[i][j][r] = 0;

    I4 a0[4], b0[2], a1[4], b1[2];

    // prologue: stage sets 0..4 into bufs 0..4 (10 vmem/wave). vmcnt(8)
    // confirms set 0; barrier publishes; read set 0 into regs A.
    STAGE(0, 0);
    STAGE(1, 1);
    STAGE(2, 2);
    STAGE(3, 3);
    STAGE(4, 4);
    VMW8();
    BARRIER();
    FRAG_READ(a0, b0, 0);

    // steady state, phase k: outstanding stages = sets k+1..k+4 (8 loads).
    // vmcnt(6) drains set k+1 (staged 4 phases ago, ~4*phase > HBM latency);
    // barrier publishes it; read set k+1; MFMA set k. Buffer b=set%6 is
    // overwritten 2 phases after its read-phase, with an intervening lgkm
    // wait (read consumer) + 2 barriers -> no WAR race.
#pragma unroll 1
    for (int kk = 0; kk < 120; kk += 6) {
        PH_S(VMW6(), kk + 5, 5, 1, a1, b1, a0, b0);   // set kk+0 (A), read kk+1
        PH_S(VMW6(), kk + 6, 0, 2, a0, b0, a1, b1);   // set kk+1 (B), read kk+2
        PH_S(VMW6(), kk + 7, 1, 3, a1, b1, a0, b0);   // set kk+2 (A), read kk+3
        PH_S(VMW6(), kk + 8, 2, 4, a0, b0, a1, b1);   // set kk+3 (B), read kk+4
        PH_S(VMW6(), kk + 9, 3, 5, a1, b1, a0, b0);   // set kk+4 (A), read kk+5
        PH_S(VMW6(), kk + 10, 4, 0, a0, b0, a1, b1);  // set kk+5 (B), read kk+6
    }
    // peel: phases 120..127 (sets 120..127; stages 125,126,127; vmcnt tapers)
    PH_S(VMW6(), 125, 5, 1, a1, b1, a0, b0);  // set 120 (A), read 121 (buf 1)
    PH_S(VMW6(), 126, 0, 2, a0, b0, a1, b1);  // set 121 (B), read 122 (buf 2)
    PH_S(VMW6(), 127, 1, 3, a1, b1, a0, b0);  // set 122 (A), read 123 (buf 3)
    PH_N(VMW6(), 4, a0, b0, a1, b1);          // set 123 (B), read 124 (buf 4)
    PH_N(VMW4(), 5, a1, b1, a0, b0);          // set 124 (A), read 125 (buf 5)
    PH_N(VMW2(), 0, a0, b0, a1, b1);          // set 125 (B), read 126 (buf 0)
    PH_N(VMW0(), 1, a1, b1, a0, b0);          // set 126 (A), read 127 (buf 1)
    LGKM0();
    SCHEDB();
    MFMA_SET(a1, b1);                         // set 127 (B)

    // epilogue: 32x32 C/D layout col=lane&31, row=(reg&3)+8*(reg>>2)+4*(lane>>5)
#pragma unroll
    for (int j = 0; j < 2; ++j) {
        const int o = bn * 256 + wc2 * 32 + j * 32 + (lane & 31);
        const int tt = t[o];
        const int sh = -nsh[o];
        const int mn = amin[o];
        const int mx = amax[o];
#pragma unroll
        for (int i = 0; i < 4; ++i) {
            const int rowbase = bm * 256 + wr4 * 32 + i * 32 + 4 * (lane >> 5);
#pragma unroll
            for (int r = 0; r < 16; ++r) {
                const int row = rowbase + (r & 3) + 8 * (r >> 2);
                int v = acc[i][j][r] + tt;
                v >>= sh;
                v = v < mn ? mn : (v > mx ? mx : v);
                __builtin_nontemporal_store(v, &out[(size_t)row * OUTDIM + o]);
            }
        }
    }
}

extern "C" void kernel_launch(void* const* d_in, const int* in_sizes, int n_in,
                              void* d_out, int out_size, void* d_ws, size_t ws_size,
                              hipStream_t stream) {
    const int* x = (const int*)d_in[0];
    const int* W = (const int*)d_in[1];
    const int* t = (const int*)d_in[2];
    const int* n = (const int*)d_in[3];
    const int* amin = (const int*)d_in[4];
    const int* amax = (const int*)d_in[5];
    int* out = (int*)d_out;

    uint8_t* xp = (uint8_t*)d_ws;                    // 33554432 B (fragment order)
    uint8_t* wp = xp + (size_t)BDIM * INDIM;         // 16777216 B (fragment order)

    pack_lds<<<1536, 256, 0, stream>>>(x, W, (uint32_t*)xp, (uint32_t*)wp);

    dim3 grid(OUTDIM / 256, BDIM / 256);  // (16 bn fast, 32 bm) = 512 blocks
    gemm_lds<<<grid, 512, 0, stream>>>(xp, wp, t, n, amin, amax, out);
}

// Round 7
// 392.818 us; speedup vs baseline: 1.0092x; 1.0092x over previous
//
#include <hip/hip_runtime.h>
#include <stdint.h>

// out[b][o] = clamp((sum_k x[b][k]*W[o][k] + t[o]) >> (-n[o]), act_min[o], act_max[o])
// B=8192, IN=4096, OUT=4096. x,W arrive int32; harness reads d_out as int32.
//
// R17: cut LDS traffic below the MFMA window. R10-R16 (6 schedule variants) all
// pin at ~1250 cy/set; common factor is 64 KB/set/CU through the LDS port
// (~724 cy at measured rates) vs a 585-cy MFMA window -- port time alone
// exceeds compute, so no schedule can hide it. Now: A stays LDS-shared (4-way
// reuse), B goes global->register directly (only 2-way reuse; packed layout is
// per-lane contiguous dwordx4). LDS/set: 8 KB writes + 32 KB reads = 458 cy <
// 585. L2 demand 24 KB/set/CU = 42 B/cy < 56 ceiling. A-stage distance 4 (6
// bufs), B-load distance 2 (3 reg sets), uniform vmcnt(3) (= one phase of
// issues), tail 3,2,2,0. B loads via inline asm; sched_barrier after barrier
// pins MFMA below its data-arrival wait.

#define BDIM 8192
#define INDIM 4096
#define OUTDIM 4096

typedef __attribute__((ext_vector_type(4))) int I4;
typedef __attribute__((ext_vector_type(16))) int I16;

// ---------------- pack: int32 -> int8 fragment order, LDS transpose ----------
// Fragment layout: byte off = ((m32*128 + kb)*64 + lane)*16 + b,
// where row = m32*32 + (lane&31), k = kb*32 + (lane>>5)*16 + b.
__global__ __launch_bounds__(256) void pack_lds(const int* __restrict__ x,
                                                const int* __restrict__ W,
                                                uint32_t* __restrict__ xp,
                                                uint32_t* __restrict__ wp) {
    __shared__ uint32_t sb[8192];  // 32 KB
    const int tid = threadIdx.x;
    const int bid = blockIdx.x;
    const int* src;
    uint32_t* dst;
    if (bid < 1024) {
        const int m32 = bid >> 2, q = bid & 3;
        src = x + (size_t)m32 * 32 * INDIM + q * 1024;
        dst = xp + (size_t)m32 * 32768 + q * 8192;
    } else {
        const int v = bid - 1024;
        const int n32 = v >> 2, q = v & 3;
        src = W + (size_t)n32 * 32 * INDIM + q * 1024;
        dst = wp + (size_t)n32 * 32768 + q * 8192;
    }
    const int kb_l = tid >> 3;                 // local kb (k/32 within chunk)
    const int lane_hi = ((tid >> 2) & 1) << 5; // (k>>4)&1 -> lane bit 5
    const int bslot = tid & 3;                 // byte-word slot within lane's 16B
#pragma unroll 4
    for (int rr = 0; rr < 32; ++rr) {
        int4 a = *(const int4*)(src + (size_t)rr * INDIM + tid * 4);
        uint32_t v = ((uint32_t)a.x & 255u) | (((uint32_t)a.y & 255u) << 8)
                   | (((uint32_t)a.z & 255u) << 16) | (((uint32_t)a.w & 255u) << 24);
        uint32_t idx = (uint32_t)(kb_l * 256 + (rr + lane_hi) * 4 + bslot);
        idx ^= ((idx >> 8) & 7u) << 2;  // XOR-swizzle: 16-way -> 2-way (free)
        sb[idx] = v;
    }
    __syncthreads();
#pragma unroll
    for (int it = 0; it < 8; ++it) {
        uint32_t idx = (uint32_t)(it * 1024 + tid * 4);
        idx ^= ((idx >> 8) & 7u) << 2;
        uint4 vv = *(const uint4*)&sb[idx];
        *(uint4*)(dst + it * 1024 + tid * 4) = vv;
    }
}

// ---------------- GEMM: 8 waves, 256x256 tile; A via LDS, B direct-to-reg ----
__device__ __forceinline__ void glds16(const void* g, void* l) {
    __builtin_amdgcn_global_load_lds((__attribute__((address_space(1))) void*)g,
                                     (__attribute__((address_space(3))) void*)l,
                                     16, 0, 0);
}

#define VMW3() asm volatile("s_waitcnt vmcnt(3)" ::: "memory")
#define VMW2() asm volatile("s_waitcnt vmcnt(2)" ::: "memory")
#define VMW0() asm volatile("s_waitcnt vmcnt(0)" ::: "memory")
#define BARRIER()                          \
    do {                                   \
        __builtin_amdgcn_s_barrier();      \
        asm volatile("" ::: "memory");     \
    } while (0)
#define SCHEDB() __builtin_amdgcn_sched_barrier(0)

// stage A-subtile w of set SETK into buffer BUF (0..5): 1 glds per wave
#define STAGE_A(SETK, BUF) \
    glds16(ga + (size_t)(SETK) * 1024, lds_raw + (BUF) * 8192 + w * 1024)

// load this wave's 2 B-subtiles of set SETK into reg pair LB (asm: no compiler
// waitcnt; arrival guaranteed by the phase-level counted vmcnt)
#define LOADB(SETK, LB)                                                           \
    do {                                                                          \
        const uint8_t* p0_ = gb0 + (size_t)(SETK) * 1024;                         \
        const uint8_t* p1_ = gb1 + (size_t)(SETK) * 1024;                         \
        asm volatile("global_load_dwordx4 %0, %1, off"                            \
                     : "=&v"(LB[0]) : "v"(p0_));                                  \
        asm volatile("global_load_dwordx4 %0, %1, off"                            \
                     : "=&v"(LB[1]) : "v"(p1_));                                  \
    } while (0)

// read this wave's 4 A-fragments of one set from buffer BUF (compile-time 0..5)
#define FRAG_READA(FA, BUF)                                                       \
    do {                                                                          \
        const uint8_t* lb_ = lds_raw + (BUF) * 8192 + lane * 16;                  \
        _Pragma("unroll")                                                         \
        for (int i_ = 0; i_ < 4; ++i_)                                            \
            FA[i_] = *(const I4*)(lb_ + (wr4 + i_) * 1024);                       \
    } while (0)

#define MFMA_SET(FA, FB)                                                          \
    do {                                                                          \
        __builtin_amdgcn_s_setprio(1);                                            \
        _Pragma("unroll")                                                         \
        for (int i_ = 0; i_ < 4; ++i_)                                            \
            _Pragma("unroll")                                                     \
            for (int j_ = 0; j_ < 2; ++j_)                                        \
                acc[i_][j_] = __builtin_amdgcn_mfma_i32_32x32x32_i8(              \
                    FA[i_], FB[j_], acc[i_][j_], 0, 0, 0);                        \
        __builtin_amdgcn_s_setprio(0);                                            \
    } while (0)

// Phase P: wait(vmcnt) -> barrier -> sched fence -> {stage A(P+4), load B(P+2),
// read A-frags(P+1)} overlapping MFMA(P).
#define PH_FULL(VMW_STMT, SSET, SBUF, LSET, LB, RBUF, RAF, MAF, MB)               \
    do {                                                                          \
        VMW_STMT;                                                                 \
        BARRIER();                                                                \
        SCHEDB();                                                                 \
        STAGE_A(SSET, SBUF);                                                      \
        LOADB(LSET, LB);                                                          \
        FRAG_READA(RAF, RBUF);                                                    \
        MFMA_SET(MAF, MB);                                                        \
    } while (0)

#define PH_NOSTAGE(VMW_STMT, LSET, LB, RBUF, RAF, MAF, MB)                        \
    do {                                                                          \
        VMW_STMT;                                                                 \
        BARRIER();                                                                \
        SCHEDB();                                                                 \
        LOADB(LSET, LB);                                                          \
        FRAG_READA(RAF, RBUF);                                                    \
        MFMA_SET(MAF, MB);                                                        \
    } while (0)

__global__ __launch_bounds__(512, 2) void gemm_lds(
    const uint8_t* __restrict__ Xp,   // fragment-ordered
    const uint8_t* __restrict__ Wp,   // fragment-ordered
    const int* __restrict__ t, const int* __restrict__ nsh,
    const int* __restrict__ amin, const int* __restrict__ amax,
    int* __restrict__ out) {

    const int bn = blockIdx.x;       // 0..15 (OUT tiles of 256) — fast axis
    const int bm = blockIdx.y;       // 0..31
    const int tid = threadIdx.x;
    const int lane = tid & 63;
    const int w = tid >> 6;          // wave 0..7
    const int wr = w >> 2;           // wave row (0..1): rows wr*128..+128
    const int wc = w & 3;            // wave col (0..3): cols wc*64..+64
    const int wr4 = wr * 4;
    const int wc2 = wc * 2;

    __shared__ uint8_t lds_raw[49152];  // 6 buffers x 8 A-subtiles x 1 KB

    // A: wave w stages subtile w (rows bm*256 + w*32)
    const uint8_t* ga = Xp + ((size_t)(bm * 8 + w) << 17) + lane * 16;
    // B: this wave's two column-subtiles, loaded direct to regs
    const uint8_t* gb0 = Wp + ((size_t)(bn * 8 + wc2 + 0) << 17) + lane * 16;
    const uint8_t* gb1 = Wp + ((size_t)(bn * 8 + wc2 + 1) << 17) + lane * 16;

    I16 acc[4][2];
#pragma unroll
    for (int i = 0; i < 4; ++i)
#pragma unroll
        for (int j = 0; j < 2; ++j)
#pragma unroll
            for (int r = 0; r < 16; ++r) acc[i][j][r] = 0;

    I4 af0[4], af1[4], b0[2], b1[2], b2[2];

    // prologue: stage A sets 0..3 (bufs 0..3), load B sets 0,1 -> b0,b1;
    // drain once (one-time), publish, read A-frags of set 0.
    STAGE_A(0, 0);
    STAGE_A(1, 1);
    STAGE_A(2, 2);
    STAGE_A(3, 3);
    LOADB(0, b0);
    LOADB(1, b1);
    VMW0();
    BARRIER();
    SCHEDB();
    FRAG_READA(af0, 0);

    // steady state, phase P: vmcnt(3) (= keep newest phase's 3 issues) drains
    // through phase P-2 -> confirms A(P+1) (staged P-3) and B(P) (loaded P-2).
    // Then stage A(P+4), load B(P+2), read frags(P+1), MFMA(P).
#pragma unroll 1
    for (int kk = 0; kk < 120; kk += 6) {
        PH_FULL(VMW3(), kk + 4, 4, kk + 2, b2, 1, af1, af0, b0);  // P=kk+0
        PH_FULL(VMW3(), kk + 5, 5, kk + 3, b0, 2, af0, af1, b1);  // P=kk+1
        PH_FULL(VMW3(), kk + 6, 0, kk + 4, b1, 3, af1, af0, b2);  // P=kk+2
        PH_FULL(VMW3(), kk + 7, 1, kk + 5, b2, 4, af0, af1, b0);  // P=kk+3
        PH_FULL(VMW3(), kk + 8, 2, kk + 6, b0, 5, af1, af0, b1);  // P=kk+4
        PH_FULL(VMW3(), kk + 9, 3, kk + 7, b1, 0, af0, af1, b2);  // P=kk+5
    }
    // peel: phases 120..127 (last A stage = set 127 @P123; last B = 127 @P125)
    PH_FULL(VMW3(), 124, 4, 122, b2, 1, af1, af0, b0);            // P=120
    PH_FULL(VMW3(), 125, 5, 123, b0, 2, af0, af1, b1);            // P=121
    PH_FULL(VMW3(), 126, 0, 124, b1, 3, af1, af0, b2);            // P=122
    PH_FULL(VMW3(), 127, 1, 125, b2, 4, af0, af1, b0);            // P=123
    PH_NOSTAGE(VMW3(), 126, b0, 5, af1, af0, b1);                 // P=124
    PH_NOSTAGE(VMW2(), 127, b1, 0, af0, af1, b2);                 // P=125
    // P=126: no stage, no load; reads set 127 (buf 1)
    VMW2();
    BARRIER();
    SCHEDB();
    FRAG_READA(af1, 1);
    MFMA_SET(af0, b0);
    // P=127
    VMW0();
    BARRIER();
    SCHEDB();
    MFMA_SET(af1, b1);

    // epilogue: 32x32 C/D layout col=lane&31, row=(reg&3)+8*(reg>>2)+4*(lane>>5)
#pragma unroll
    for (int j = 0; j < 2; ++j) {
        const int o = bn * 256 + wc2 * 32 + j * 32 + (lane & 31);
        const int tt = t[o];
        const int sh = -nsh[o];
        const int mn = amin[o];
        const int mx = amax[o];
#pragma unroll
        for (int i = 0; i < 4; ++i) {
            const int rowbase = bm * 256 + wr4 * 32 + i * 32 + 4 * (lane >> 5);
#pragma unroll
            for (int r = 0; r < 16; ++r) {
                const int row = rowbase + (r & 3) + 8 * (r >> 2);
                int v = acc[i][j][r] + tt;
                v >>= sh;
                v = v < mn ? mn : (v > mx ? mx : v);
                __builtin_nontemporal_store(v, &out[(size_t)row * OUTDIM + o]);
            }
        }
    }
}

extern "C" void kernel_launch(void* const* d_in, const int* in_sizes, int n_in,
                              void* d_out, int out_size, void* d_ws, size_t ws_size,
                              hipStream_t stream) {
    const int* x = (const int*)d_in[0];
    const int* W = (const int*)d_in[1];
    const int* t = (const int*)d_in[2];
    const int* n = (const int*)d_in[3];
    const int* amin = (const int*)d_in[4];
    const int* amax = (const int*)d_in[5];
    int* out = (int*)d_out;

    uint8_t* xp = (uint8_t*)d_ws;                    // 33554432 B (fragment order)
    uint8_t* wp = xp + (size_t)BDIM * INDIM;         // 16777216 B (fragment order)

    pack_lds<<<1536, 256, 0, stream>>>(x, W, (uint32_t*)xp, (uint32_t*)wp);

    dim3 grid(OUTDIM / 256, BDIM / 256);  // (16 bn fast, 32 bm) = 512 blocks
    gemm_lds<<<grid, 512, 0, stream>>>(xp, wp, t, n, amin, amax, out);
}